// Round 10
// baseline (127.193 us; speedup 1.0000x reference)
//
#include <hip/hip_runtime.h>

// Frozen problem constants
#define RAD   4
#define KS    9          // kernel size 2R+1
#define HALO  8          // 2*RAD
#define SS    17         // KS + 2*RAD (staged neighborhood per dim)
#define DIM   256        // volume is 256^3
#define SIG   1.2f

// ---------------------------------------------------------------------------
// Blur fix-up: one block per point (proven round-1/3/7 code, absmax 0.0,
// ~5us). Stage 17^3 neighborhood in LDS (zero-filled OOB == zero-padded
// conv), separable z/y/x passes, write the clipped 9^3 region voxels.
// Runs after the bulk D2D copy via stream ordering. Overlapping boxes write
// bitwise-identical values -> benign race.
// ---------------------------------------------------------------------------
__global__ __launch_bounds__(256) void blur_fix_kernel(
    const float* __restrict__ vol, const int* __restrict__ pts,
    float* __restrict__ out) {
    __shared__ float sm[SS * SS * SS];   // 4913 floats
    __shared__ float t1[KS * SS * SS];   // 9 x 17 x 17
    __shared__ float t2[KS * KS * SS];   // 9 x 9 x 17

    const int p   = blockIdx.x;
    const int tid = threadIdx.x;
    const int pz = pts[3 * p + 0];
    const int py = pts[3 * p + 1];
    const int px = pts[3 * p + 2];

    // Gaussian weights, same fp32 arithmetic as reference (expf + sum)
    float g[KS];
    {
        float s = 0.f;
        #pragma unroll
        for (int i = 0; i < KS; ++i) {
            float x = (float)(i - RAD);
            g[i] = expf(-(x * x) / (2.f * SIG * SIG));
            s += g[i];
        }
        float inv = 1.f / s;
        #pragma unroll
        for (int i = 0; i < KS; ++i) g[i] *= inv;
    }

    // Stage 17^3 neighborhood, zeros outside the volume
    for (int idx = tid; idx < SS * SS * SS; idx += 256) {
        int k = idx % SS;
        int j = (idx / SS) % SS;
        int i = idx / (SS * SS);
        int z = pz - HALO + i;
        int y = py - HALO + j;
        int x = px - HALO + k;
        float v = 0.f;
        if ((unsigned)z < (unsigned)DIM && (unsigned)y < (unsigned)DIM &&
            (unsigned)x < (unsigned)DIM) {
            v = vol[(z << 16) + (y << 8) + x];
        }
        sm[idx] = v;
    }
    __syncthreads();

    // Pass 1: z
    for (int idx = tid; idx < KS * SS * SS; idx += 256) {
        int k = idx % SS;
        int j = (idx / SS) % SS;
        int i = idx / (SS * SS);
        float acc = 0.f;
        #pragma unroll
        for (int t = 0; t < KS; ++t)
            acc += g[t] * sm[(((i + t) * SS) + j) * SS + k];
        t1[idx] = acc;
    }
    __syncthreads();

    // Pass 2: y
    for (int idx = tid; idx < KS * KS * SS; idx += 256) {
        int k = idx % SS;
        int j = (idx / SS) % KS;
        int i = idx / (SS * KS);
        float acc = 0.f;
        #pragma unroll
        for (int t = 0; t < KS; ++t)
            acc += g[t] * t1[((i * SS) + (j + t)) * SS + k];
        t2[((i * KS) + j) * SS + k] = acc;
    }
    __syncthreads();

    // Pass 3: x + scatter clipped 9^3 outputs
    for (int idx = tid; idx < KS * KS * KS; idx += 256) {
        int k = idx % KS;
        int j = (idx / KS) % KS;
        int i = idx / (KS * KS);
        float acc = 0.f;
        #pragma unroll
        for (int t = 0; t < KS; ++t)
            acc += g[t] * t2[((i * KS) + j) * SS + (k + t)];
        int z = pz - RAD + i;
        int y = py - RAD + j;
        int x = px - RAD + k;
        if ((unsigned)z < (unsigned)DIM && (unsigned)y < (unsigned)DIM &&
            (unsigned)x < (unsigned)DIM) {
            out[(z << 16) + (y << 8) + x] = acc;
        }
    }
}

extern "C" void kernel_launch(void* const* d_in, const int* in_sizes, int n_in,
                              void* d_out, int out_size, void* d_ws, size_t ws_size,
                              hipStream_t stream) {
    const float* vol = (const float*)d_in[0];
    const int*   pts = (const int*)d_in[1];
    float*       out = (float*)d_out;

    const int n   = in_sizes[0];          // 256^3 = 16777216
    const int npt = in_sizes[1] / 3;      // 6 points

    // Bulk copy via the runtime's tuned D2D path (graph-capture-safe per
    // harness rules), then overwrite the region voxels with blurred values.
    hipMemcpyAsync(out, vol, (size_t)n * sizeof(float),
                   hipMemcpyDeviceToDevice, stream);
    blur_fix_kernel<<<npt, 256, 0, stream>>>(vol, pts, out);
}

// Round 11
// 117.525 us; speedup vs baseline: 1.0823x; 1.0823x over previous
//
#include <hip/hip_runtime.h>

// Frozen problem constants
#define RAD   4
#define KS    9
#define HALO  8
#define SS    17
#define DIM   256
#define SIG   1.2f
#define IT    8                 // float4s per thread in a copy block
#define CHUNK (256 * IT)        // float4s per copy block (32 rows of one z-slice)

// ---------------------------------------------------------------------------
// Single fused kernel, write-disjoint (round-7 configuration — best measured:
// 117.7us total, absmax 0.0):
//   blocks [0, NPT)        : blur blocks — LDS-staged separable 9^3 Gaussian.
//                            Write exactly the clipped region voxels.
//   blocks [NPT, NPT+2048) : copy blocks — write everything EXCEPT region
//                            voxels. Block-uniform hit test; common path is a
//                            branch-free unrolled float4 copy.
// Lessons encoded: no per-iter branches in the copy loop (round 2: 20x slow);
// no direct conv from global (round 6: 200us serial-load tail); single launch
// beats copy-kernel+fixup (round 3: +7us) and memcpyAsync+fixup (round 10: +9us).
// ---------------------------------------------------------------------------
template <int NPT>
__global__ __launch_bounds__(256) void fused_kernel(
    const float* __restrict__ vol, const int* __restrict__ pts,
    float* __restrict__ out, int n4) {

    // 4913 (sm) + 2601 (t1) floats = 30 KB; t2 aliases sm (dead after pass 1).
    __shared__ float lds[SS * SS * SS + KS * SS * SS];

    const int tid = threadIdx.x;

    if ((int)blockIdx.x < NPT) {
        float* sm = lds;
        float* t1 = lds + SS * SS * SS;
        float* t2 = lds;   // alias of sm — only written after sm's last read

        const int p  = blockIdx.x;
        const int pz = pts[3 * p + 0];
        const int py = pts[3 * p + 1];
        const int px = pts[3 * p + 2];

        // Gaussian weights, same fp32 arithmetic as reference (expf + sum)
        float g[KS];
        {
            float s = 0.f;
            #pragma unroll
            for (int i = 0; i < KS; ++i) {
                float x = (float)(i - RAD);
                g[i] = expf(-(x * x) / (2.f * SIG * SIG));
                s += g[i];
            }
            float inv = 1.f / s;
            #pragma unroll
            for (int i = 0; i < KS; ++i) g[i] *= inv;
        }

        // Stage 17^3 neighborhood, zero-filled OOB (== zero-padded conv)
        for (int idx = tid; idx < SS * SS * SS; idx += 256) {
            int k = idx % SS;
            int j = (idx / SS) % SS;
            int i = idx / (SS * SS);
            int z = pz - HALO + i;
            int y = py - HALO + j;
            int x = px - HALO + k;
            float v = 0.f;
            if ((unsigned)z < (unsigned)DIM && (unsigned)y < (unsigned)DIM &&
                (unsigned)x < (unsigned)DIM) {
                v = vol[(z << 16) + (y << 8) + x];
            }
            sm[idx] = v;
        }
        __syncthreads();

        // Pass 1: z
        for (int idx = tid; idx < KS * SS * SS; idx += 256) {
            int k = idx % SS;
            int j = (idx / SS) % SS;
            int i = idx / (SS * SS);
            float acc = 0.f;
            #pragma unroll
            for (int t = 0; t < KS; ++t)
                acc += g[t] * sm[(((i + t) * SS) + j) * SS + k];
            t1[idx] = acc;
        }
        __syncthreads();   // after this, sm is dead -> t2 may overwrite it

        // Pass 2: y
        for (int idx = tid; idx < KS * KS * SS; idx += 256) {
            int k = idx % SS;
            int j = (idx / SS) % KS;
            int i = idx / (SS * KS);
            float acc = 0.f;
            #pragma unroll
            for (int t = 0; t < KS; ++t)
                acc += g[t] * t1[((i * SS) + (j + t)) * SS + k];
            t2[((i * KS) + j) * SS + k] = acc;
        }
        __syncthreads();

        // Pass 3: x + scatter clipped 9^3 outputs (exactly the region voxels)
        for (int idx = tid; idx < KS * KS * KS; idx += 256) {
            int k = idx % KS;
            int j = (idx / KS) % KS;
            int i = idx / (KS * KS);
            float acc = 0.f;
            #pragma unroll
            for (int t = 0; t < KS; ++t)
                acc += g[t] * t2[((i * KS) + j) * SS + (k + t)];
            int z = pz - RAD + i;
            int y = py - RAD + j;
            int x = px - RAD + k;
            if ((unsigned)z < (unsigned)DIM && (unsigned)y < (unsigned)DIM &&
                (unsigned)x < (unsigned)DIM) {
                out[(z << 16) + (y << 8) + x] = acc;
            }
        }
        return;
    }

    // ---------------- copy block ----------------
    const int c    = blockIdx.x - NPT;
    const int base = c * CHUNK;              // float4 index
    const int zb   = base >> 14;             // 16384 float4 per z-slice
    const int y0   = (base & 16383) >> 6;    // rows [y0, y0+32)

    int pzr[NPT], pyr[NPT], pxr[NPT];
    #pragma unroll
    for (int p = 0; p < NPT; ++p) {
        pzr[p] = pts[3 * p + 0];
        pyr[p] = pts[3 * p + 1];
        pxr[p] = pts[3 * p + 2];
    }

    bool hit = false;
    #pragma unroll
    for (int p = 0; p < NPT; ++p)
        hit |= (abs(zb - pzr[p]) <= RAD) & (pyr[p] + RAD >= y0) &
               (pyr[p] - RAD <= y0 + 31);

    const float4* __restrict__ in4  = (const float4*)vol;
    float4* __restrict__       out4 = (float4*)out;

    const bool full = (base + CHUNK <= n4);   // always true for 256^3

    if (!hit && full) {
        // Branch-free, fully unrolled: all 8 loads batched in flight.
        #pragma unroll
        for (int it = 0; it < IT; ++it) {
            const int i4 = base + it * 256 + tid;
            out4[i4] = in4[i4];
        }
    } else {
        // Rare (~5% of blocks): per-float4 test; scalar stores only where a
        // float4 straddles the region boundary. Compare-only — no conv.
        for (int it = 0; it < IT; ++it) {
            const int i4 = base + it * 256 + tid;
            if (i4 >= n4) break;
            const float4 v = in4[i4];
            const int lin = i4 << 2;
            const int x0  = lin & (DIM - 1);
            const int y   = (lin >> 8) & (DIM - 1);
            const int z   = lin >> 16;
            bool h4 = false;
            #pragma unroll
            for (int p = 0; p < NPT; ++p)
                h4 |= (abs(z - pzr[p]) <= RAD) & (abs(y - pyr[p]) <= RAD) &
                      (x0 <= pxr[p] + RAD) & (x0 + 3 >= pxr[p] - RAD);
            if (!h4) {
                out4[i4] = v;
            } else {
                const float r[4] = {v.x, v.y, v.z, v.w};
                #pragma unroll
                for (int e = 0; e < 4; ++e) {
                    const int x = x0 + e;
                    bool ins = false;
                    #pragma unroll
                    for (int p = 0; p < NPT; ++p)
                        ins |= (abs(z - pzr[p]) <= RAD) &
                               (abs(y - pyr[p]) <= RAD) &
                               (abs(x - pxr[p]) <= RAD);
                    if (!ins) out[lin + e] = r[e];
                }
            }
        }
    }
}

template <int NPT>
static void launch_fused(const float* vol, const int* pts, float* out,
                         int n4, hipStream_t stream) {
    const int nCopyBlk = (n4 + CHUNK - 1) / CHUNK;   // 2048 for 256^3
    fused_kernel<NPT><<<NPT + nCopyBlk, 256, 0, stream>>>(vol, pts, out, n4);
}

extern "C" void kernel_launch(void* const* d_in, const int* in_sizes, int n_in,
                              void* d_out, int out_size, void* d_ws, size_t ws_size,
                              hipStream_t stream) {
    const float* vol = (const float*)d_in[0];
    const int*   pts = (const int*)d_in[1];
    float*       out = (float*)d_out;

    const int n   = in_sizes[0];           // 256^3
    const int n4  = n / 4;
    const int npt = in_sizes[1] / 3;       // 6 (reference range 5..7)

    switch (npt) {
        case 1: launch_fused<1>(vol, pts, out, n4, stream); break;
        case 2: launch_fused<2>(vol, pts, out, n4, stream); break;
        case 3: launch_fused<3>(vol, pts, out, n4, stream); break;
        case 4: launch_fused<4>(vol, pts, out, n4, stream); break;
        case 5: launch_fused<5>(vol, pts, out, n4, stream); break;
        case 6: launch_fused<6>(vol, pts, out, n4, stream); break;
        default: launch_fused<7>(vol, pts, out, n4, stream); break;
    }
}